// Round 11
// baseline (877.799 us; speedup 1.0000x reference)
//
#include <hip/hip_runtime.h>

typedef float    f32x4 __attribute__((ext_vector_type(4)));
typedef _Float16 f16x8 __attribute__((ext_vector_type(8)));

#define BATCH 131072
#define SEQT  20
#define L1F  1.4426950408889634f   // log2(e)
#define L2F  2.8853900817779268f   // 2*log2(e)

// ---------- fast activations ----------
__device__ __forceinline__ float fexp2(float x){ return __builtin_amdgcn_exp2f(x); }
__device__ __forceinline__ float frcp (float x){ return __builtin_amdgcn_rcpf(x); }

__device__ __forceinline__ f32x4 MFMA(f16x8 a, f16x8 b, f32x4 c){
  return __builtin_amdgcn_mfma_f32_16x16x32_f16(a, b, c, 0, 0, 0);
}
__device__ __forceinline__ f16x8 zero8h(){
  f16x8 z;
#pragma unroll
  for (int e=0;e<8;++e) z[e]=(_Float16)0.f;
  return z;
}

// volatile 16B LDS frag read: not LICM-hoistable, but schedulable vs non-volatile ops
__device__ __forceinline__ f16x8 ldsfrag(const _Float16* p){
  return *(volatile const f16x8*)p;
}

// pack two f32x4 (sigma-contiguous halves) into one pre-scaled f16x8 frag (RNE cvt)
__device__ __forceinline__ f16x8 pack8h(f32x4 lo, f32x4 hi, float sc){
  f16x8 f;
#pragma unroll
  for (int e=0;e<4;++e){ f[e] = (_Float16)(sc*lo[e]); f[4+e] = (_Float16)(sc*hi[e]); }
  return f;
}
// K=32 sigma-frag from global: cols {4kg..4kg+3, 16+4kg..16+4kg+3} = two aligned f32x4
__device__ __forceinline__ f16x8 gfragH(const float* __restrict__ W, int row, int kg, float sc){
  f32x4 lo = *(const f32x4*)(W + row*32 + 4*kg);
  f32x4 hi = *(const f32x4*)(W + row*32 + 16 + 4*kg);
  return pack8h(lo, hi, sc);
}
__device__ __forceinline__ f32x4 ld4(const float* __restrict__ p){ return *(const f32x4*)p; }

// ---------- gate nonlinearity + state update + fp16 pack ----------
// Pre-scaled z (i,f,o by log2e; g by 2log2e): 5 exp2 + 2 rcp + ~13 VALU per element.
__device__ __forceinline__ void activate(const f32x4* acc, float* cs, f16x8& ph){
  float hv[8];
#pragma unroll
  for (int mm=0; mm<2; ++mm)
#pragma unroll
  for (int r=0; r<4; ++r){
    const int e = mm*4 + r;
    float zi = acc[0+mm][r];
    float zf = acc[2+mm][r];
    float zg = acc[4+mm][r];
    float zo = acc[6+mm][r];
    float A  = fexp2(-zi);
    float F  = fexp2(-zf);
    float B  = fexp2(zg);
    float ab = (1.0f+A)*(B+1.0f);
    float fp = 1.0f+F;
    float r1 = frcp(ab*fp);
    // cn = r1*( ab*c + (B-1)*fp ),  (B-1)*fp = fma(B,fp,-fp)
    float cn = r1 * fmaf(ab, cs[e], fmaf(B, fp, -fp));
    cs[e] = cn;
    float E  = fexp2(-zo);
    float D  = fexp2(L2F*cn);
    hv[e] = (D-1.0f)*frcp((1.0f+E)*(D+1.0f));       // sigm(zo)*tanh(cn)
  }
  f16x8 P;
#pragma unroll
  for (int e=0;e<8;++e) P[e] = (_Float16)hv[e];
  ph = P;
}

__global__ __launch_bounds__(256, 3) void lstm_ae_mfma(
    const float* __restrict__ x,
    const float* __restrict__ eWih0, const float* __restrict__ eWhh0,
    const float* __restrict__ ebih0, const float* __restrict__ ebhh0,
    const float* __restrict__ eWih1, const float* __restrict__ eWhh1,
    const float* __restrict__ ebih1, const float* __restrict__ ebhh1,
    const float* __restrict__ bnW,   const float* __restrict__ bnB,
    const float* __restrict__ exW,   const float* __restrict__ exB,
    const float* __restrict__ dWih0, const float* __restrict__ dWhh0,
    const float* __restrict__ dbih0, const float* __restrict__ dbhh0,
    const float* __restrict__ dWih1, const float* __restrict__ dWhh1,
    const float* __restrict__ dbih1, const float* __restrict__ dbhh1,
    const float* __restrict__ outW,  const float* __restrict__ outB,
    float* __restrict__ out)
{
  const int tid  = threadIdx.x;
  const int lane = tid & 63;
  const int w    = tid >> 6;      // wave id (0..3)
  const int cl   = lane & 15;     // batch col within wave / A-frag row
  const int kg   = lane >> 4;     // k-group (0..3)

  // LDS: biases (+zero slot) + weight frags (enc/dec shared) + 10-step output staging
  __shared__ __align__(16) float    sb[592];
  __shared__ __align__(16) _Float16 sfrag[13312];   // 1664 frags x 16B = 26.6 KB
  __shared__ __align__(16) float    sout[3200];     // 64 bb x 10 t x 5 f = 12.8 KB

  // ---- bias prep (bih+bhh, pre-scaled: g rows x2log2e, others xlog2e) ----
  if (tid < 128){
    float sc = (tid >= 64 && tid < 96) ? L2F : L1F;
    sb[128 + tid] = sc*(ebih1[tid] + ebhh1[tid]);
    sb[384 + tid] = sc*(dbih1[tid] + dbhh1[tid]);
  }
  if (tid < 16) sb[512 + tid] = (tid < 5) ? outB[tid] : 0.0f;
  if (tid < 16) sb[576 + tid] = 0.0f;          // 16B zero slot

  // ---- stage ENCODER weight frags (fp16, pre-scaled) ----
  // [0]=Whh0 (8m x 64lane), [512]=Wih1, [1024]=Whh1, [1536]=Wih0+bias (8m x 16cl)
#pragma unroll
  for (int q=0; q<6; ++q){
    int tile = w + 4*q;                 // 0..23
    int mat  = tile >> 3, m = tile & 7;
    float sc = (m==4 || m==5) ? L2F : L1F;
    const float* Wm = (mat==0) ? eWhh0 : (mat==1) ? eWih1 : eWhh1;
    f16x8 f = gfragH(Wm, m*16+cl, kg, sc);
    *(f16x8*)&sfrag[(mat*512 + m*64 + lane)*8] = f;
  }
  if (tid < 128){
    int m = tid >> 4, r = tid & 15;
    float sc = (m==4 || m==5) ? L2F : L1F;
    int row = m*16 + r;
    float b  = sc*(ebih0[row] + ebhh0[row]);
    _Float16 bh = (_Float16)b;
    float bl = b - (float)bh;
    f16x8 f;
#pragma unroll
    for (int e=0;e<5;++e) f[e] = (_Float16)(sc*eWih0[row*5+e]);
    f[5] = bh; f[6] = (_Float16)bl; f[7] = (_Float16)0.f;
    *(f16x8*)&sfrag[(1536 + m*16 + r)*8] = f;
  }
  __syncthreads();

  // ---- preload layer-1 bias into registers ----
  f32x4 rb1[8];
#pragma unroll
  for (int m=0;m<8;++m) rb1[m] = *(const f32x4*)&sb[128 + m*16 + kg*4];

  f32x4 acc[8], accB[8];
  float cs0[8], cs1[8];
#pragma unroll
  for (int e=0;e<8;++e){ cs0[e]=0.f; cs1[e]=0.f; }
  f16x8 ph0 = zero8h(), ph1 = zero8h();

  // Wih0 frag address: kg==0 lanes real, others the 16B zero slot (stride 0)
  const _Float16* wih0p = (kg==0) ? &sfrag[(1536 + cl)*8] : (const _Float16*)&sb[576];
  const unsigned wih0s = (kg==0) ? 128u : 0u;   // per-m stride in halves

  const long blockb = (long)blockIdx.x * 64;
  const float* __restrict__ xcol = x + (blockb + (w*16+cl))*100;

  // ---- encoder prologue: t=0 layer0 (h0=0 -> z = Wih0@[x,1,1]) ----
  f16x8 xf = zero8h();
  if (kg==0){
    f16x8 X;
    X[0]=(_Float16)xcol[0]; X[1]=(_Float16)xcol[1]; X[2]=(_Float16)xcol[2];
    X[3]=(_Float16)xcol[3]; X[4]=(_Float16)xcol[4];
    X[5]=(_Float16)1.f; X[6]=(_Float16)1.f; X[7]=(_Float16)0.f;
    xf = X;
  }
#pragma unroll
  for (int m=0; m<8; ++m){
    const f16x8 fb = ldsfrag(&wih0p[m*wih0s]);
    f32x4 b = {0.f,0.f,0.f,0.f};
    acc[m] = MFMA(fb, xf, b);
  }
  activate(acc, cs0, ph0);
  float xv0=0.f,xv1=0.f,xv2=0.f,xv3=0.f,xv4=0.f;   // x(t+1)
  if (kg==0){ xv0=xcol[5]; xv1=xcol[6]; xv2=xcol[7]; xv3=xcol[8]; xv4=xcol[9]; }

  // ================= encoder main (t = 0..18) =================
#pragma unroll 1
  for (int t=0; t<SEQT-1; ++t){
    // prefetch x(t+2)
    float xn0=0.f,xn1=0.f,xn2=0.f,xn3=0.f,xn4=0.f;
    if (kg==0 && t < SEQT-2){
      const float* xp = xcol + (t+2)*5;
      xn0=xp[0]; xn1=xp[1]; xn2=xp[2]; xn3=xp[3]; xn4=xp[4];
    }
    // layer1 MFMAs for step t (ph1(t-1), ph0(t))
#pragma unroll
    for (int m=0; m<8; ++m){
      const f16x8 fd = ldsfrag(&sfrag[(1024 + m*64 + lane)*8]);
      const f16x8 fc = ldsfrag(&sfrag[( 512 + m*64 + lane)*8]);
      f32x4 b = rb1[m];
      b = MFMA(fd, ph1, b);
      b = MFMA(fc, ph0, b);
      accB[m] = b;
    }
    // layer0 MFMAs for step t+1 (ph0(t), x(t+1)) — overlaps activate1
    if (kg==0){
      f16x8 X;
      X[0]=(_Float16)xv0; X[1]=(_Float16)xv1; X[2]=(_Float16)xv2;
      X[3]=(_Float16)xv3; X[4]=(_Float16)xv4;
      X[5]=(_Float16)1.f; X[6]=(_Float16)1.f; X[7]=(_Float16)0.f;
      xf = X;
    }
#pragma unroll
    for (int m=0; m<8; ++m){
      const f16x8 fa = ldsfrag(&sfrag[(m*64 + lane)*8]);
      const f16x8 fb = ldsfrag(&wih0p[m*wih0s]);
      f32x4 b = {0.f,0.f,0.f,0.f};
      b = MFMA(fa, ph0, b);
      b = MFMA(fb, xf , b);
      acc[m] = b;
    }
    activate(accB, cs1, ph1);
    activate(acc,  cs0, ph0);
    xv0=xn0; xv1=xn1; xv2=xn2; xv3=xn3; xv4=xn4;
  }
  // encoder epilogue: t=19 layer1 only
  {
#pragma unroll
    for (int m=0; m<8; ++m){
      const f16x8 fd = ldsfrag(&sfrag[(1024 + m*64 + lane)*8]);
      const f16x8 fc = ldsfrag(&sfrag[( 512 + m*64 + lane)*8]);
      f32x4 b = rb1[m];
      b = MFMA(fd, ph1, b);
      b = MFMA(fc, ph0, b);
      accB[m] = b;
    }
    activate(accB, cs1, ph1);
  }
  __syncthreads();   // all waves done with enc frags

  // ---- stage DECODER weight frags (overwrites enc region; pre-scaled) ----
#pragma unroll
  for (int q=0; q<6; ++q){
    int tile = w + 4*q;
    int mat  = tile >> 3, m = tile & 7;
    float sc = (m==4 || m==5) ? L2F : L1F;
    const float* Wm = (mat==0) ? dWhh0 : (mat==1) ? dWih1 : dWhh1;
    f16x8 f = gfragH(Wm, m*16+cl, kg, sc);
    *(f16x8*)&sfrag[(mat*512 + m*64 + lane)*8] = f;
  }
  if (tid < 64){
    int r2 = tid & 15, k2 = tid >> 4;
    f16x8 f = (r2 < 5) ? gfragH(outW, r2, k2, 1.0f) : zero8h();
    *(f16x8*)&sfrag[(1536 + tid)*8] = f;
  }

  // ---- bottleneck (registers + global weight reads; fp16, no residual) ----
  f32x4 dpre[8];
  {
    f16x8 WBN = gfragH(bnW, cl, kg, 1.0f);
    f32x4 aL = ld4(bnB + kg*4);
    aL = MFMA(WBN, ph1, aL);
    f16x8 ltf = zero8h();
#pragma unroll
    for (int r=0; r<4; ++r) ltf[r] = (_Float16)fmaxf(aL[r], 0.0f);
    f32x4 aE[2];
#pragma unroll
    for (int mm=0; mm<2; ++mm){
      const int row = mm*16 + cl;
      f32x4 we = ld4(exW + row*16 + 4*kg);
      f16x8 X = zero8h();
#pragma unroll
      for (int e=0;e<4;++e) X[e] = (_Float16)we[e];
      f32x4 b = ld4(exB + mm*16 + kg*4);
      aE[mm] = MFMA(X, ltf, b);
    }
    f16x8 exf;
#pragma unroll
    for (int e=0; e<8; ++e) exf[e] = (_Float16)fmaxf(aE[e>>2][e&3], 0.0f);
#pragma unroll
    for (int m=0; m<8; ++m){
      const float sc = (m==4 || m==5) ? L2F : L1F;
      f16x8 wm = gfragH(dWih0, m*16+cl, kg, sc);
      f32x4 b = sc*( ld4(dbih0 + m*16 + kg*4) + ld4(dbhh0 + m*16 + kg*4) );
      dpre[m] = MFMA(wm, exf, b);
    }
  }

  // reset state; reload rb1 with decoder layer-1 biases
#pragma unroll
  for (int e=0;e<8;++e){ cs0[e]=0.f; cs1[e]=0.f; }
  ph0 = zero8h(); ph1 = zero8h();

  __syncthreads();   // dec frags staged
#pragma unroll
  for (int m=0;m<8;++m) rb1[m] = *(const f32x4*)&sb[384 + m*16 + kg*4];

  const f32x4 obias = *(const f32x4*)&sb[512 + kg*4];
  float* __restrict__ ob = out + blockb*100;
  const int sobase = (w*16 + cl)*50;

  // ---- decoder prologue: t=0 layer0 (h0=0 -> z0 = dpre) ----
  activate(dpre, cs0, ph0);

  // ================= decoder main (t = 0..18) =================
#pragma unroll 1
  for (int t=0; t<SEQT-1; ++t){
    // layer1 MFMAs for step t
#pragma unroll
    for (int m=0; m<8; ++m){
      const f16x8 fd = ldsfrag(&sfrag[(1024 + m*64 + lane)*8]);
      const f16x8 fc = ldsfrag(&sfrag[( 512 + m*64 + lane)*8]);
      f32x4 b = rb1[m];
      b = MFMA(fd, ph1, b);
      b = MFMA(fc, ph0, b);
      accB[m] = b;
    }
    // layer0 MFMAs for step t+1 (dpre + Whh0d@h0)
#pragma unroll
    for (int m=0; m<8; ++m){
      const f16x8 fa = ldsfrag(&sfrag[(m*64 + lane)*8]);
      acc[m] = MFMA(fa, ph0, dpre[m]);
    }
    activate(accB, cs1, ph1);
    // output projection for step t (needs new ph1) — overlaps activate0
    const f16x8 fo = ldsfrag(&sfrag[(1536 + lane)*8]);
    f32x4 o = MFMA(fo, ph1, obias);
    activate(acc, cs0, ph0);
    // stage output (10-step chunks)
    int ts = (t >= 10) ? t-10 : t;
    if (kg == 0){
      sout[sobase + ts*5 + 0] = o[0];
      sout[sobase + ts*5 + 1] = o[1];
      sout[sobase + ts*5 + 2] = o[2];
      sout[sobase + ts*5 + 3] = o[3];
    } else if (kg == 1){
      sout[sobase + ts*5 + 4] = o[0];
    }
    if (t == 9){
      __syncthreads();
      for (int i=tid; i<3200; i+=256){
        int bb = i/50, off = i - bb*50;
        ob[bb*100 + off] = sout[i];
      }
      __syncthreads();
    }
  }
  // decoder epilogue: t=19 (layer1 + out-proj only) -> ts=9 of chunk 2
  {
#pragma unroll
    for (int m=0; m<8; ++m){
      const f16x8 fd = ldsfrag(&sfrag[(1024 + m*64 + lane)*8]);
      const f16x8 fc = ldsfrag(&sfrag[( 512 + m*64 + lane)*8]);
      f32x4 b = rb1[m];
      b = MFMA(fd, ph1, b);
      b = MFMA(fc, ph0, b);
      accB[m] = b;
    }
    activate(accB, cs1, ph1);
    const f16x8 fo = ldsfrag(&sfrag[(1536 + lane)*8]);
    f32x4 o = MFMA(fo, ph1, obias);
    if (kg == 0){
      sout[sobase + 45 + 0] = o[0];
      sout[sobase + 45 + 1] = o[1];
      sout[sobase + 45 + 2] = o[2];
      sout[sobase + 45 + 3] = o[3];
    } else if (kg == 1){
      sout[sobase + 45 + 4] = o[0];
    }
  }
  __syncthreads();
  for (int i=tid; i<3200; i+=256){
    int bb = i/50, off = i - bb*50;
    ob[bb*100 + 50 + off] = sout[i];
  }
}

extern "C" void kernel_launch(void* const* d_in, const int* in_sizes, int n_in,
                              void* d_out, int out_size, void* d_ws, size_t ws_size,
                              hipStream_t stream)
{
  const float* x     = (const float*)d_in[0];
  const float* eWih0 = (const float*)d_in[1];
  const float* eWhh0 = (const float*)d_in[2];
  const float* ebih0 = (const float*)d_in[3];
  const float* ebhh0 = (const float*)d_in[4];
  const float* eWih1 = (const float*)d_in[5];
  const float* eWhh1 = (const float*)d_in[6];
  const float* ebih1 = (const float*)d_in[7];
  const float* ebhh1 = (const float*)d_in[8];
  const float* bnW   = (const float*)d_in[9];
  const float* bnB   = (const float*)d_in[10];
  const float* exW   = (const float*)d_in[11];
  const float* exB   = (const float*)d_in[12];
  const float* dWih0 = (const float*)d_in[13];
  const float* dWhh0 = (const float*)d_in[14];
  const float* dbih0 = (const float*)d_in[15];
  const float* dbhh0 = (const float*)d_in[16];
  const float* dWih1 = (const float*)d_in[17];
  const float* dWhh1 = (const float*)d_in[18];
  const float* dbih1 = (const float*)d_in[19];
  const float* dbhh1 = (const float*)d_in[20];
  const float* outW  = (const float*)d_in[21];
  const float* outB  = (const float*)d_in[22];

  dim3 grid(BATCH / 64), block(256);
  hipLaunchKernelGGL(lstm_ae_mfma, grid, block, 0, stream,
                     x,
                     eWih0, eWhh0, ebih0, ebhh0,
                     eWih1, eWhh1, ebih1, ebhh1,
                     bnW, bnB, exW, exB,
                     dWih0, dWhh0, dbih0, dbhh0,
                     dWih1, dWhh1, dbih1, dbhh1,
                     outW, outB,
                     (float*)d_out);
}

// Round 12
// 339.293 us; speedup vs baseline: 2.5871x; 2.5871x over previous
//
#include <hip/hip_runtime.h>

typedef float    f32x4 __attribute__((ext_vector_type(4)));
typedef _Float16 f16x8 __attribute__((ext_vector_type(8)));

#define BATCH 131072
#define SEQT  20
#define L1F  1.4426950408889634f   // log2(e)
#define L2F  2.8853900817779268f   // 2*log2(e)

// ---------- fast activations ----------
__device__ __forceinline__ float fexp2(float x){ return __builtin_amdgcn_exp2f(x); }
__device__ __forceinline__ float frcp (float x){ return __builtin_amdgcn_rcpf(x); }

__device__ __forceinline__ f32x4 MFMA(f16x8 a, f16x8 b, f32x4 c){
  return __builtin_amdgcn_mfma_f32_16x16x32_f16(a, b, c, 0, 0, 0);
}
__device__ __forceinline__ f16x8 zero8h(){
  f16x8 z;
#pragma unroll
  for (int e=0;e<8;++e) z[e]=(_Float16)0.f;
  return z;
}

// pack two f32x4 (sigma-contiguous halves) into one pre-scaled f16x8 frag (RNE cvt)
__device__ __forceinline__ f16x8 pack8h(f32x4 lo, f32x4 hi, float sc){
  f16x8 f;
#pragma unroll
  for (int e=0;e<4;++e){ f[e] = (_Float16)(sc*lo[e]); f[4+e] = (_Float16)(sc*hi[e]); }
  return f;
}
// K=32 sigma-frag from global: cols {4kg..4kg+3, 16+4kg..16+4kg+3} = two aligned f32x4
__device__ __forceinline__ f16x8 gfragH(const float* __restrict__ W, int row, int kg, float sc){
  f32x4 lo = *(const f32x4*)(W + row*32 + 4*kg);
  f32x4 hi = *(const f32x4*)(W + row*32 + 16 + 4*kg);
  return pack8h(lo, hi, sc);
}
__device__ __forceinline__ f32x4 ld4(const float* __restrict__ p){ return *(const f32x4*)p; }

// ---------- gate nonlinearity + state update + fp16 pack ----------
// Pre-scaled z (i,f,o by log2e; g by 2log2e): 5 exp2 + 2 rcp per element. No residual.
__device__ __forceinline__ void activate(const f32x4* acc, float* cs, f16x8& ph){
  float hv[8];
#pragma unroll
  for (int mm=0; mm<2; ++mm)
#pragma unroll
  for (int r=0; r<4; ++r){
    const int e = mm*4 + r;
    float zi = acc[0+mm][r];
    float zf = acc[2+mm][r];
    float zg = acc[4+mm][r];
    float zo = acc[6+mm][r];
    float A  = fexp2(-zi);
    float F  = fexp2(-zf);
    float B  = fexp2(zg);
    float ab = (1.0f+A)*(B+1.0f);
    float fp = 1.0f+F;
    float r1 = frcp(ab*fp);
    float cn = fmaf(ab*r1, cs[e], (B-1.0f)*fp*r1);  // sigm(zf)*c + sigm(zi)*tanh(zg)
    cs[e] = cn;
    float E  = fexp2(-zo);
    float D  = fexp2(L2F*cn);
    hv[e] = (D-1.0f)*frcp((1.0f+E)*(D+1.0f));       // sigm(zo)*tanh(cn)
  }
  f16x8 P;
#pragma unroll
  for (int e=0;e<8;++e) P[e] = (_Float16)hv[e];
  ph = P;
}

__global__ __launch_bounds__(256, 3) void lstm_ae_mfma(
    const float* __restrict__ x,
    const float* __restrict__ eWih0, const float* __restrict__ eWhh0,
    const float* __restrict__ ebih0, const float* __restrict__ ebhh0,
    const float* __restrict__ eWih1, const float* __restrict__ eWhh1,
    const float* __restrict__ ebih1, const float* __restrict__ ebhh1,
    const float* __restrict__ bnW,   const float* __restrict__ bnB,
    const float* __restrict__ exW,   const float* __restrict__ exB,
    const float* __restrict__ dWih0, const float* __restrict__ dWhh0,
    const float* __restrict__ dbih0, const float* __restrict__ dbhh0,
    const float* __restrict__ dWih1, const float* __restrict__ dWhh1,
    const float* __restrict__ dbih1, const float* __restrict__ dbhh1,
    const float* __restrict__ outW,  const float* __restrict__ outB,
    float* __restrict__ out)
{
  const int tid  = threadIdx.x;
  const int lane = tid & 63;
  const int w    = tid >> 6;      // wave id (0..3)
  const int cl   = lane & 15;     // batch col within wave / A-frag row
  const int kg   = lane >> 4;     // k-group (0..3)

  // LDS: biases (+zero slot) + weight frags (enc/dec shared) + 10-step output staging
  __shared__ __align__(16) float    sb[592];
  __shared__ __align__(16) _Float16 sfrag[13312];   // 1664 frags x 16B = 26.6 KB
  __shared__ __align__(16) float    sout[3200];     // 64 bb x 10 t x 5 f = 12.8 KB

  // ---- bias prep (bih+bhh, pre-scaled: g rows x2log2e, others xlog2e) ----
  if (tid < 128){
    float sc = (tid >= 64 && tid < 96) ? L2F : L1F;
    sb[128 + tid] = sc*(ebih1[tid] + ebhh1[tid]);
    sb[384 + tid] = sc*(dbih1[tid] + dbhh1[tid]);
  }
  if (tid < 16) sb[512 + tid] = (tid < 5) ? outB[tid] : 0.0f;
  if (tid < 16) sb[576 + tid] = 0.0f;          // 16B+ zero slot

  // ---- stage ENCODER weight frags (fp16, pre-scaled) ----
  // [0]=Whh0 (8m x 64lane), [512]=Wih1, [1024]=Whh1, [1536]=Wih0+bias (8m x 16cl)
#pragma unroll
  for (int q=0; q<6; ++q){
    int tile = w + 4*q;                 // 0..23
    int mat  = tile >> 3, m = tile & 7;
    float sc = (m==4 || m==5) ? L2F : L1F;
    const float* Wm = (mat==0) ? eWhh0 : (mat==1) ? eWih1 : eWhh1;
    f16x8 f = gfragH(Wm, m*16+cl, kg, sc);
    *(f16x8*)&sfrag[(mat*512 + m*64 + lane)*8] = f;
  }
  if (tid < 128){
    int m = tid >> 4, r = tid & 15;
    float sc = (m==4 || m==5) ? L2F : L1F;
    int row = m*16 + r;
    float b  = sc*(ebih0[row] + ebhh0[row]);
    _Float16 bh = (_Float16)b;
    float bl = b - (float)bh;
    f16x8 f;
#pragma unroll
    for (int e=0;e<5;++e) f[e] = (_Float16)(sc*eWih0[row*5+e]);
    f[5] = bh; f[6] = (_Float16)bl; f[7] = (_Float16)0.f;
    *(f16x8*)&sfrag[(1536 + m*16 + r)*8] = f;
  }
  __syncthreads();

  // ---- preload layer-1 bias into registers ----
  f32x4 rb1[8];
#pragma unroll
  for (int m=0;m<8;++m) rb1[m] = *(const f32x4*)&sb[128 + m*16 + kg*4];

  f32x4 acc[8], accB[8];
  float cs0[8], cs1[8];
#pragma unroll
  for (int e=0;e<8;++e){ cs0[e]=0.f; cs1[e]=0.f; }
  f16x8 ph0 = zero8h(), ph1 = zero8h();

  // Wih0 frag address: kg==0 lanes real, others the 16B zero slot (stride 0)
  const _Float16* wih0p = (kg==0) ? &sfrag[(1536 + cl)*8] : (const _Float16*)&sb[576];
  const unsigned wih0s = (kg==0) ? 128u : 0u;   // per-m stride in halves

  const long blockb = (long)blockIdx.x * 64;
  const float* __restrict__ xcol = x + (blockb + (w*16+cl))*100;

  // ---- encoder prologue: t=0 layer0 (h0=0 -> z = Wih0@[x,1,1]) ----
  f16x8 xf = zero8h();
  if (kg==0){
    f16x8 X;
    X[0]=(_Float16)xcol[0]; X[1]=(_Float16)xcol[1]; X[2]=(_Float16)xcol[2];
    X[3]=(_Float16)xcol[3]; X[4]=(_Float16)xcol[4];
    X[5]=(_Float16)1.f; X[6]=(_Float16)1.f; X[7]=(_Float16)0.f;
    xf = X;
  }
#pragma unroll
  for (int m=0; m<8; ++m){
    const f16x8 fb = *(const f16x8*)&wih0p[m*wih0s];
    f32x4 b = {0.f,0.f,0.f,0.f};
    acc[m] = MFMA(fb, xf, b);
  }
  activate(acc, cs0, ph0);
  float xv0=0.f,xv1=0.f,xv2=0.f,xv3=0.f,xv4=0.f;   // x(t+1)
  if (kg==0){ xv0=xcol[5]; xv1=xcol[6]; xv2=xcol[7]; xv3=xcol[8]; xv4=xcol[9]; }

  // ================= encoder main (t = 0..18) =================
#pragma unroll 1
  for (int t=0; t<SEQT-1; ++t){
    asm volatile("" ::: "memory");
    // prefetch x(t+2)
    float xn0=0.f,xn1=0.f,xn2=0.f,xn3=0.f,xn4=0.f;
    if (kg==0 && t < SEQT-2){
      const float* xp = xcol + (t+2)*5;
      xn0=xp[0]; xn1=xp[1]; xn2=xp[2]; xn3=xp[3]; xn4=xp[4];
    }
    // layer1 MFMAs for step t (ph1(t-1), ph0(t))
#pragma unroll
    for (int m=0; m<8; ++m){
      const f16x8 fd = *(const f16x8*)&sfrag[(1024 + m*64 + lane)*8];
      const f16x8 fc = *(const f16x8*)&sfrag[( 512 + m*64 + lane)*8];
      f32x4 b = rb1[m];
      b = MFMA(fd, ph1, b);
      b = MFMA(fc, ph0, b);
      accB[m] = b;
    }
    // layer0 MFMAs for step t+1 (ph0(t), x(t+1)) — overlaps activate1
    if (kg==0){
      f16x8 X;
      X[0]=(_Float16)xv0; X[1]=(_Float16)xv1; X[2]=(_Float16)xv2;
      X[3]=(_Float16)xv3; X[4]=(_Float16)xv4;
      X[5]=(_Float16)1.f; X[6]=(_Float16)1.f; X[7]=(_Float16)0.f;
      xf = X;
    }
#pragma unroll
    for (int m=0; m<8; ++m){
      const f16x8 fa = *(const f16x8*)&sfrag[(m*64 + lane)*8];
      const f16x8 fb = *(const f16x8*)&wih0p[m*wih0s];
      f32x4 b = {0.f,0.f,0.f,0.f};
      b = MFMA(fa, ph0, b);
      b = MFMA(fb, xf , b);
      acc[m] = b;
    }
    activate(accB, cs1, ph1);
    activate(acc,  cs0, ph0);
    xv0=xn0; xv1=xn1; xv2=xn2; xv3=xn3; xv4=xn4;
  }
  // encoder epilogue: t=19 layer1 only
  {
#pragma unroll
    for (int m=0; m<8; ++m){
      const f16x8 fd = *(const f16x8*)&sfrag[(1024 + m*64 + lane)*8];
      const f16x8 fc = *(const f16x8*)&sfrag[( 512 + m*64 + lane)*8];
      f32x4 b = rb1[m];
      b = MFMA(fd, ph1, b);
      b = MFMA(fc, ph0, b);
      accB[m] = b;
    }
    activate(accB, cs1, ph1);
  }
  __syncthreads();   // all waves done with enc frags

  // ---- stage DECODER weight frags (overwrites enc region; pre-scaled) ----
#pragma unroll
  for (int q=0; q<6; ++q){
    int tile = w + 4*q;
    int mat  = tile >> 3, m = tile & 7;
    float sc = (m==4 || m==5) ? L2F : L1F;
    const float* Wm = (mat==0) ? dWhh0 : (mat==1) ? dWih1 : dWhh1;
    f16x8 f = gfragH(Wm, m*16+cl, kg, sc);
    *(f16x8*)&sfrag[(mat*512 + m*64 + lane)*8] = f;
  }
  if (tid < 64){
    int r2 = tid & 15, k2 = tid >> 4;
    f16x8 f = (r2 < 5) ? gfragH(outW, r2, k2, 1.0f) : zero8h();
    *(f16x8*)&sfrag[(1536 + tid)*8] = f;
  }

  // ---- bottleneck (registers + global weight reads; fp16, no residual) ----
  f32x4 dpre[8];
  {
    f16x8 WBN = gfragH(bnW, cl, kg, 1.0f);
    f32x4 aL = ld4(bnB + kg*4);
    aL = MFMA(WBN, ph1, aL);
    f16x8 ltf = zero8h();
#pragma unroll
    for (int r=0; r<4; ++r) ltf[r] = (_Float16)fmaxf(aL[r], 0.0f);
    f32x4 aE[2];
#pragma unroll
    for (int mm=0; mm<2; ++mm){
      const int row = mm*16 + cl;
      f32x4 we = ld4(exW + row*16 + 4*kg);
      f16x8 X = zero8h();
#pragma unroll
      for (int e=0;e<4;++e) X[e] = (_Float16)we[e];
      f32x4 b = ld4(exB + mm*16 + kg*4);
      aE[mm] = MFMA(X, ltf, b);
    }
    f16x8 exf;
#pragma unroll
    for (int e=0; e<8; ++e) exf[e] = (_Float16)fmaxf(aE[e>>2][e&3], 0.0f);
#pragma unroll
    for (int m=0; m<8; ++m){
      const float sc = (m==4 || m==5) ? L2F : L1F;
      f16x8 wm = gfragH(dWih0, m*16+cl, kg, sc);
      f32x4 b = sc*( ld4(dbih0 + m*16 + kg*4) + ld4(dbhh0 + m*16 + kg*4) );
      dpre[m] = MFMA(wm, exf, b);
    }
  }

  // reset state; reload rb1 with decoder layer-1 biases
#pragma unroll
  for (int e=0;e<8;++e){ cs0[e]=0.f; cs1[e]=0.f; }
  ph0 = zero8h(); ph1 = zero8h();

  __syncthreads();   // dec frags staged
#pragma unroll
  for (int m=0;m<8;++m) rb1[m] = *(const f32x4*)&sb[384 + m*16 + kg*4];

  const f32x4 obias = *(const f32x4*)&sb[512 + kg*4];
  float* __restrict__ ob = out + blockb*100;
  const int sobase = (w*16 + cl)*50;

  // ---- decoder prologue: t=0 layer0 (h0=0 -> z0 = dpre) ----
  activate(dpre, cs0, ph0);

  // ================= decoder main (t = 0..18) =================
#pragma unroll 1
  for (int t=0; t<SEQT-1; ++t){
    asm volatile("" ::: "memory");
    // layer1 MFMAs for step t
#pragma unroll
    for (int m=0; m<8; ++m){
      const f16x8 fd = *(const f16x8*)&sfrag[(1024 + m*64 + lane)*8];
      const f16x8 fc = *(const f16x8*)&sfrag[( 512 + m*64 + lane)*8];
      f32x4 b = rb1[m];
      b = MFMA(fd, ph1, b);
      b = MFMA(fc, ph0, b);
      accB[m] = b;
    }
    // layer0 MFMAs for step t+1 (dpre + Whh0d@h0)
#pragma unroll
    for (int m=0; m<8; ++m){
      const f16x8 fa = *(const f16x8*)&sfrag[(m*64 + lane)*8];
      acc[m] = MFMA(fa, ph0, dpre[m]);
    }
    activate(accB, cs1, ph1);
    // output projection for step t (needs new ph1) — overlaps activate0
    const f16x8 fo = *(const f16x8*)&sfrag[(1536 + lane)*8];
    f32x4 o = MFMA(fo, ph1, obias);
    activate(acc, cs0, ph0);
    // stage output
    int ts = (t >= 10) ? t-10 : t;
    if (kg == 0){
      sout[sobase + ts*5 + 0] = o[0];
      sout[sobase + ts*5 + 1] = o[1];
      sout[sobase + ts*5 + 2] = o[2];
      sout[sobase + ts*5 + 3] = o[3];
    } else if (kg == 1){
      sout[sobase + ts*5 + 4] = o[0];
    }
    if (t == 9){
      __syncthreads();
      for (int i=tid; i<3200; i+=256){
        int bb = i/50, off = i - bb*50;
        ob[bb*100 + off] = sout[i];
      }
      __syncthreads();
    }
  }
  // decoder epilogue: t=19 (layer1 + out-proj only)
  {
#pragma unroll
    for (int m=0; m<8; ++m){
      const f16x8 fd = *(const f16x8*)&sfrag[(1024 + m*64 + lane)*8];
      const f16x8 fc = *(const f16x8*)&sfrag[( 512 + m*64 + lane)*8];
      f32x4 b = rb1[m];
      b = MFMA(fd, ph1, b);
      b = MFMA(fc, ph0, b);
      accB[m] = b;
    }
    activate(accB, cs1, ph1);
    const f16x8 fo = *(const f16x8*)&sfrag[(1536 + lane)*8];
    f32x4 o = MFMA(fo, ph1, obias);
    if (kg == 0){
      sout[sobase + 45 + 0] = o[0];
      sout[sobase + 45 + 1] = o[1];
      sout[sobase + 45 + 2] = o[2];
      sout[sobase + 45 + 3] = o[3];
    } else if (kg == 1){
      sout[sobase + 45 + 4] = o[0];
    }
  }
  __syncthreads();
  for (int i=tid; i<3200; i+=256){
    int bb = i/50, off = i - bb*50;
    ob[bb*100 + 50 + off] = sout[i];
  }
}

extern "C" void kernel_launch(void* const* d_in, const int* in_sizes, int n_in,
                              void* d_out, int out_size, void* d_ws, size_t ws_size,
                              hipStream_t stream)
{
  const float* x     = (const float*)d_in[0];
  const float* eWih0 = (const float*)d_in[1];
  const float* eWhh0 = (const float*)d_in[2];
  const float* ebih0 = (const float*)d_in[3];
  const float* ebhh0 = (const float*)d_in[4];
  const float* eWih1 = (const float*)d_in[5];
  const float* eWhh1 = (const float*)d_in[6];
  const float* ebih1 = (const float*)d_in[7];
  const float* ebhh1 = (const float*)d_in[8];
  const float* bnW   = (const float*)d_in[9];
  const float* bnB   = (const float*)d_in[10];
  const float* exW   = (const float*)d_in[11];
  const float* exB   = (const float*)d_in[12];
  const float* dWih0 = (const float*)d_in[13];
  const float* dWhh0 = (const float*)d_in[14];
  const float* dbih0 = (const float*)d_in[15];
  const float* dbhh0 = (const float*)d_in[16];
  const float* dWih1 = (const float*)d_in[17];
  const float* dWhh1 = (const float*)d_in[18];
  const float* dbih1 = (const float*)d_in[19];
  const float* dbhh1 = (const float*)d_in[20];
  const float* outW  = (const float*)d_in[21];
  const float* outB  = (const float*)d_in[22];

  dim3 grid(BATCH / 64), block(256);
  hipLaunchKernelGGL(lstm_ae_mfma, grid, block, 0, stream,
                     x,
                     eWih0, eWhh0, ebih0, ebhh0,
                     eWih1, eWhh1, ebih1, ebhh1,
                     bnW, bnB, exW, exB,
                     dWih0, dWhh0, dbih0, dbhh0,
                     dWih1, dWhh1, dbih1, dbhh1,
                     outW, outB,
                     (float*)d_out);
}